// Round 3
// baseline (1331.591 us; speedup 1.0000x reference)
//
#include <hip/hip_runtime.h>

// MHA fused forward on gfx950.
// B=4, S=2048, E=2048, H=16, D=128; M = B*S = 8192.
// Outputs (concat in d_out): out (B,S,E) fp32 | k (B,H,S,D) fp32 | v (B,H,S,D) fp32.

typedef unsigned short u16;
typedef unsigned int   u32;
typedef float  f32x4  __attribute__((ext_vector_type(4)));
typedef __bf16 bf16x8 __attribute__((ext_vector_type(8)));

#define B_  4
#define S_  2048
#define E_  2048
#define H_  16
#define D_  128

__device__ __forceinline__ u16 f2bf(float f) {
    union { float f; u32 u; } v; v.f = f;
    return (u16)((v.u + 0x8000u) >> 16);
}
__device__ __forceinline__ u32 pack_bf(float a, float b) {
    union { float f; u32 u; } x, y; x.f = a; y.f = b;
    return ((x.u + 0x8000u) >> 16) | ((y.u + 0x8000u) & 0xFFFF0000u);
}
__device__ __forceinline__ float bf2f(u16 h) {
    union { u32 u; float f; } v; v.u = ((u32)h) << 16; return v.f;
}

// async global->LDS, 16B/lane. LDS dest = wave-uniform base + lane*16.
__device__ __forceinline__ void gld16(const u16* g, u16* l) {
    __builtin_amdgcn_global_load_lds(
        (const __attribute__((address_space(1))) void*)g,
        (__attribute__((address_space(3))) void*)l, 16, 0, 0);
}

// ---------------------------------------------------------------------------
// x (fp32) -> bf16, 8 elems/thread
// ---------------------------------------------------------------------------
__global__ __launch_bounds__(256) void xconv_kernel(
    const float* __restrict__ x, u16* __restrict__ xb)
{
    size_t g = (size_t)blockIdx.x * 256 + threadIdx.x;
    const float4* p = (const float4*)x + g * 2;
    float4 a = p[0], b = p[1];
    uint4 pk;
    pk.x = pack_bf(a.x, a.y); pk.y = pack_bf(a.z, a.w);
    pk.z = pack_bf(b.x, b.y); pk.w = pack_bf(b.z, b.w);
    ((uint4*)xb)[g] = pk;
}

// ---------------------------------------------------------------------------
// Transpose + convert: W (K x N fp32) -> WT (N x K bf16)
// ---------------------------------------------------------------------------
__global__ __launch_bounds__(256) void wtrans_kernel(
    const float* __restrict__ W, u16* __restrict__ WT, int K, int N)
{
    __shared__ float tile[64][65];
    const int n0 = blockIdx.x * 64, k0 = blockIdx.y * 64;
    const int t = threadIdx.x;
#pragma unroll
    for (int i = 0; i < 16; ++i) {
        int idx = i * 256 + t; int r = idx >> 6, c = idx & 63;
        tile[r][c] = W[(size_t)(k0 + r) * N + n0 + c];
    }
    __syncthreads();
#pragma unroll
    for (int i = 0; i < 16; ++i) {
        int idx = i * 256 + t; int rn = idx >> 6, ck = idx & 63;
        WT[(size_t)(n0 + rn) * K + k0 + ck] = f2bf(tile[ck][rn]);
    }
}

// ---------------------------------------------------------------------------
// GEMM: C = A (M x K bf16) * Bt^T (Bt N x K bf16).
// 256x256 tile, BK=64, 512 threads (8 waves as 2Mx4N), per-wave out 128x64.
// 8-phase (4 per K-tile) counted-vmcnt schedule (T3+T4), chunk-XOR swizzled
// LDS (T2-equivalent: chunk ^= row&7; pre-swizzled global source + linear
// global_load_lds dest), setprio(1) around MFMA clusters (T5).
// LDS = 2 dbuf x (A 32KB + B 32KB) = 128 KB -> 1 block/CU, 2 waves/SIMD.
// ---------------------------------------------------------------------------
__device__ __forceinline__ void stage_half(
    const u16* __restrict__ g, int K, u16* l, int t)
{
    const int wb = (t >> 6) << 6;          // wave*64
#pragma unroll
    for (int j = 0; j < 2; ++j) {
        const int idx = j * 512 + t;
        const int row = idx >> 3, c = (idx & 7) ^ (row & 7);
        gld16(g + (size_t)row * K + (c << 3),
              l + ((j * 512 + wb) << 3));
    }
}

template <int MODE>
__global__ __launch_bounds__(512, 2) void gemm_kernel(
    const u16* __restrict__ A, const u16* __restrict__ Bt,
    const float* __restrict__ bias,
    u16* __restrict__ qh, u16* __restrict__ kh, u16* __restrict__ vt,
    float* __restrict__ vout, float* __restrict__ outf,
    int N, int K)
{
    __shared__ u16 Asm[2][256 * 64];       // 2 x 32 KB
    __shared__ u16 Bsm[2][256 * 64];       // 2 x 32 KB

    const int t = threadIdx.x;
    const int wave = t >> 6, lane = t & 63, quad = lane >> 4, l16 = lane & 15;
    const int wr = wave >> 2, wc = wave & 3;
    const int m0 = blockIdx.y * 256, n0 = blockIdx.x * 256;
    const int NT = K >> 6;

    // swizzled read offsets: logical chunk = kk*4+quad; row&7 == l16&7
    const int sw0 = ((quad ^ (l16 & 7)) << 3);
    const int sw1 = (((4 + quad) ^ (l16 & 7)) << 3);
    const int aRow = (wr * 128 + l16) << 6;   // row*64 u16
    const int bRow = (wc * 64 + l16) << 6;

    f32x4 acc[8][4] = {};

    const u16* Ab = A  + (size_t)m0 * K;
    const u16* Bb = Bt + (size_t)n0 * K;

    // prologue: tile0 A+B, tile1 A. vmcnt(4) -> tile0 fully landed.
    stage_half(Ab,                        K, &Asm[0][0],    t);
    stage_half(Ab + (size_t)128 * K,      K, &Asm[0][8192], t);
    stage_half(Bb,                        K, &Bsm[0][0],    t);
    stage_half(Bb + (size_t)128 * K,      K, &Bsm[0][8192], t);
    stage_half(Ab + 64,                   K, &Asm[1][0],    t);
    stage_half(Ab + (size_t)128 * K + 64, K, &Asm[1][8192], t);
    asm volatile("s_waitcnt vmcnt(4)" ::: "memory");
    __builtin_amdgcn_s_barrier();

    for (int T = 0; T < NT; ++T) {
        const int cur = T & 1, nxt = cur ^ 1;
        const int kn1 = (T + 1) << 6, kn2 = (T + 2) << 6;
        const u16* Asb = &Asm[cur][0];
        const u16* Bsb = &Bsm[cur][0];
        bf16x8 af[8], b0, b1;

        // ---- phase 0: kk=0, ni=0,1 ; stage B(T+1) h0 ----
#pragma unroll
        for (int mi = 0; mi < 8; ++mi)
            af[mi] = *(const bf16x8*)(Asb + aRow + mi * 1024 + sw0);
        b0 = *(const bf16x8*)(Bsb + bRow + sw0);
        b1 = *(const bf16x8*)(Bsb + bRow + 1024 + sw0);
        if (T + 1 < NT) stage_half(Bb + kn1, K, &Bsm[nxt][0], t);
        __builtin_amdgcn_s_barrier();
        asm volatile("s_waitcnt lgkmcnt(0)" ::: "memory");
        __builtin_amdgcn_s_setprio(1);
#pragma unroll
        for (int mi = 0; mi < 8; ++mi) {
            acc[mi][0] = __builtin_amdgcn_mfma_f32_16x16x32_bf16(af[mi], b0, acc[mi][0], 0, 0, 0);
            acc[mi][1] = __builtin_amdgcn_mfma_f32_16x16x32_bf16(af[mi], b1, acc[mi][1], 0, 0, 0);
        }
        __builtin_amdgcn_s_setprio(0);
        __builtin_amdgcn_s_barrier();

        // ---- phase 1: kk=0, ni=2,3 ; stage B(T+1) h1 ----
        b0 = *(const bf16x8*)(Bsb + bRow + 2048 + sw0);
        b1 = *(const bf16x8*)(Bsb + bRow + 3072 + sw0);
        if (T + 1 < NT) stage_half(Bb + (size_t)128 * K + kn1, K, &Bsm[nxt][8192], t);
        __builtin_amdgcn_s_barrier();
        asm volatile("s_waitcnt lgkmcnt(0)" ::: "memory");
        __builtin_amdgcn_s_setprio(1);
#pragma unroll
        for (int mi = 0; mi < 8; ++mi) {
            acc[mi][2] = __builtin_amdgcn_mfma_f32_16x16x32_bf16(af[mi], b0, acc[mi][2], 0, 0, 0);
            acc[mi][3] = __builtin_amdgcn_mfma_f32_16x16x32_bf16(af[mi], b1, acc[mi][3], 0, 0, 0);
        }
        __builtin_amdgcn_s_setprio(0);
        __builtin_amdgcn_s_barrier();

        // ---- phase 2: kk=1, ni=0,1 (last ds_read of As[cur]) ----
#pragma unroll
        for (int mi = 0; mi < 8; ++mi)
            af[mi] = *(const bf16x8*)(Asb + aRow + mi * 1024 + sw1);
        b0 = *(const bf16x8*)(Bsb + bRow + sw1);
        b1 = *(const bf16x8*)(Bsb + bRow + 1024 + sw1);
        __builtin_amdgcn_s_barrier();
        asm volatile("s_waitcnt lgkmcnt(0)" ::: "memory");
        __builtin_amdgcn_s_setprio(1);
#pragma unroll
        for (int mi = 0; mi < 8; ++mi) {
            acc[mi][0] = __builtin_amdgcn_mfma_f32_16x16x32_bf16(af[mi], b0, acc[mi][0], 0, 0, 0);
            acc[mi][1] = __builtin_amdgcn_mfma_f32_16x16x32_bf16(af[mi], b1, acc[mi][1], 0, 0, 0);
        }
        __builtin_amdgcn_s_setprio(0);
        __builtin_amdgcn_s_barrier();

        // ---- phase 3: kk=1, ni=2,3 ; stage A(T+2) ; counted vmcnt ----
        b0 = *(const bf16x8*)(Bsb + bRow + 2048 + sw1);
        b1 = *(const bf16x8*)(Bsb + bRow + 3072 + sw1);
        if (T + 2 < NT) {
            stage_half(Ab + kn2,                   K, &Asm[cur][0],    t);
            stage_half(Ab + (size_t)128 * K + kn2, K, &Asm[cur][8192], t);
        }
        __builtin_amdgcn_s_barrier();
        asm volatile("s_waitcnt lgkmcnt(0)" ::: "memory");
        __builtin_amdgcn_s_setprio(1);
#pragma unroll
        for (int mi = 0; mi < 8; ++mi) {
            acc[mi][2] = __builtin_amdgcn_mfma_f32_16x16x32_bf16(af[mi], b0, acc[mi][2], 0, 0, 0);
            acc[mi][3] = __builtin_amdgcn_mfma_f32_16x16x32_bf16(af[mi], b1, acc[mi][3], 0, 0, 0);
        }
        __builtin_amdgcn_s_setprio(0);
        if (T + 2 < NT) { asm volatile("s_waitcnt vmcnt(4)" ::: "memory"); }
        else            { asm volatile("s_waitcnt vmcnt(0)" ::: "memory"); }
        __builtin_amdgcn_s_barrier();
    }

    if constexpr (MODE == 0) {
        const int sel = n0 >> 11;                  // 0=q 1=k 2=v
        const int b   = m0 >> 11, sb = m0 & 2047;
#pragma unroll
        for (int ni = 0; ni < 4; ++ni) {
            const int dg = (n0 & 2047) + wc * 64 + ni * 16 + l16;
            const int h = dg >> 7, d = dg & 127;
            const float bv = bias[n0 + wc * 64 + ni * 16 + l16];
            const size_t hb = ((size_t)(b * H_ + h)) * S_ * D_;
#pragma unroll
            for (int mi = 0; mi < 8; ++mi) {
                const int s0 = sb + wr * 128 + mi * 16 + quad * 4;
                float v0 = acc[mi][ni][0] + bv, v1 = acc[mi][ni][1] + bv;
                float v2 = acc[mi][ni][2] + bv, v3 = acc[mi][ni][3] + bv;
                size_t base = hb + (size_t)s0 * D_ + d;
                if (sel < 2) {
                    u16* dst = sel ? kh : qh;
                    dst[base]        = f2bf(v0); dst[base + D_]    = f2bf(v1);
                    dst[base + 2*D_] = f2bf(v2); dst[base + 3*D_]  = f2bf(v3);
                } else {
                    vout[base] = v0; vout[base + D_] = v1;
                    vout[base + 2*D_] = v2; vout[base + 3*D_] = v3;
                    uint2 pk; pk.x = pack_bf(v0, v1); pk.y = pack_bf(v2, v3);
                    *(uint2*)(vt + ((size_t)(b * H_ + h) * D_ + d) * S_ + s0) = pk;
                }
            }
        }
    } else {
#pragma unroll
        for (int ni = 0; ni < 4; ++ni) {
            const int col = n0 + wc * 64 + ni * 16 + l16;
            const float bv = bias[col];
#pragma unroll
            for (int mi = 0; mi < 8; ++mi) {
                const int row0 = m0 + wr * 128 + mi * 16 + quad * 4;
#pragma unroll
                for (int r = 0; r < 4; ++r)
                    outf[(size_t)(row0 + r) * N + col] = acc[mi][ni][r] + bv;
            }
        }
    }
}

// ---------------------------------------------------------------------------
// Rotary: in-place on qh/kh (bf16), k fp32 -> d_out. Folds 1/sqrt(D)*log2(e)
// into q (softmax done in base-2).
// ---------------------------------------------------------------------------
__global__ __launch_bounds__(256) void rotary_kernel(
    u16* __restrict__ q, u16* __restrict__ k, float* __restrict__ kout,
    const float* __restrict__ cosT, const float* __restrict__ sinT)
{
    const int g = blockIdx.x * 256 + threadIdx.x;
    const int d0 = (g & 15) << 3;
    const int srow = g >> 4;
    const int s = srow & (S_ - 1);
    const size_t base = (size_t)srow * D_ + d0;

    uint4 qv = *(const uint4*)(q + base);
    uint4 kv = *(const uint4*)(k + base);
    float cc[8], ss[8];
    *(float4*)(cc)     = *(const float4*)(cosT + s * D_ + d0);
    *(float4*)(cc + 4) = *(const float4*)(cosT + s * D_ + d0 + 4);
    *(float4*)(ss)     = *(const float4*)(sinT + s * D_ + d0);
    *(float4*)(ss + 4) = *(const float4*)(sinT + s * D_ + d0 + 4);
    const u16* qp = (const u16*)&qv; const u16* kp = (const u16*)&kv;
    float qo[8], ko[8];
#pragma unroll
    for (int i = 0; i < 4; ++i) {
        float q1 = bf2f(qp[2*i]), q2 = bf2f(qp[2*i+1]);
        float k1 = bf2f(kp[2*i]), k2 = bf2f(kp[2*i+1]);
        qo[2*i]   = q1 * cc[2*i]   - q2 * ss[2*i];
        qo[2*i+1] = q2 * cc[2*i+1] + q1 * ss[2*i+1];
        ko[2*i]   = k1 * cc[2*i]   - k2 * ss[2*i];
        ko[2*i+1] = k2 * cc[2*i+1] + k1 * ss[2*i+1];
    }
    const float qs_ = 0.08838834764831845f * 1.4426950408889634f; // 1/sqrt(D)*log2e
    uint4 qpk, kpk;
    u32* qq = (u32*)&qpk; u32* kq = (u32*)&kpk;
#pragma unroll
    for (int i = 0; i < 4; ++i) {
        qq[i] = pack_bf(qo[2*i] * qs_, qo[2*i+1] * qs_);
        kq[i] = pack_bf(ko[2*i], ko[2*i+1]);
    }
    *(uint4*)(q + base) = qpk;
    *(uint4*)(k + base) = kpk;
    *(float4*)(kout + base)     = make_float4(ko[0], ko[1], ko[2], ko[3]);
    *(float4*)(kout + base + 4) = make_float4(ko[4], ko[5], ko[6], ko[7]);
}

// ---------------------------------------------------------------------------
// Flash attention. Br=64 (wave = 16 q-rows), Bc=64. S^T = K*Q^T so the C
// register index runs along keys -> packed b64 P-stores + 2-shuffle softmax.
// Q frags direct from global. Single-buffered swizzled LDS (40 KB -> 4
// blocks/CU for TLP) + T14 async-STAGE split: tile t+1 loaded into REGISTERS
// (8 x dwordx4) before computing tile t from LDS; after the barrier the regs
// are ds_written (swizzle on the write address). T13 defer-max (THR=8,
// base-2) skips O-rescale on stable-max tiles. T5 setprio around MFMA.
// ---------------------------------------------------------------------------
#define KSWZ(row, c) ((row) * 128 + (((c) ^ ((row) & 7)) << 3))  // 64 x 16-chunk
#define VSWZ(d, c)   ((d) * 64 + (((c) ^ ((d) & 7)) << 3))       // 128 x 8-chunk
#define PSWZ(qr, c)  ((qr) * 64 + (((c) ^ ((qr) & 7)) << 3))     // 16 x 8-chunk

__global__ __launch_bounds__(256, 4) void attn_kernel(
    const u16* __restrict__ qh, const u16* __restrict__ kh,
    const u16* __restrict__ vt, u16* __restrict__ yb)
{
    __shared__ u16 Ks[64 * 128];        // 16 KB
    __shared__ u16 Vs[128 * 64];        // 16 KB  (V^T tile [d][key])
    __shared__ u16 Ps[4 * 16 * 64];     //  8 KB  (per-wave P [q][key])

    const int t = threadIdx.x, wave = t >> 6, lane = t & 63;
    const int quad = lane >> 4, l16 = lane & 15;
    const int bh = blockIdx.y, q0 = blockIdx.x * 64;
    const u16* kb = kh + (size_t)bh * S_ * D_;
    const u16* vb = vt + (size_t)bh * D_ * S_;
    u16* Pw = Ps + wave * (16 * 64);

    // per-thread staging addresses (linear global; swizzle applied on ds_write)
    const int krow = t >> 4, kc = t & 15;          // K: rows 0-15 per i-step of 16
    const int vrow = t >> 3, vc = t & 7;           // V^T: d-rows 0-31 per i-step of 32
    uint4 gk[4], gv[4];

    auto stage_load = [&](int k0) {
#pragma unroll
        for (int i = 0; i < 4; ++i) {
            gk[i] = *(const uint4*)(kb + (size_t)(k0 + i * 16 + krow) * D_ + (kc << 3));
            gv[i] = *(const uint4*)(vb + (size_t)(i * 32 + vrow) * S_ + k0 + (vc << 3));
        }
    };
    auto stage_write = [&]() {
#pragma unroll
        for (int i = 0; i < 4; ++i) {
            *(uint4*)(Ks + KSWZ(i * 16 + krow, kc)) = gk[i];
            *(uint4*)(Vs + VSWZ(i * 32 + vrow, vc)) = gv[i];
        }
    };

    // Q fragments (B-operand layout: n=l16 q-row, k=quad*8) straight from global
    bf16x8 qf[4];
    {
        const u16* qp = qh + ((size_t)bh * S_ + q0 + wave * 16 + l16) * D_ + quad * 8;
#pragma unroll
        for (int kk = 0; kk < 4; ++kk) qf[kk] = *(const bf16x8*)(qp + kk * 32);
    }

    f32x4 o[8] = {};
    float m_r = -1e30f, l_r = 0.f;      // per-lane: q-row = l16 (replicated over quads)

    stage_load(0);
    stage_write();                       // compiler inserts vmcnt before use
    __syncthreads();

    for (int k0 = 0; k0 < S_; k0 += 64) {
        const bool more = (k0 + 64 < S_);
        if (more) stage_load(k0 + 64);   // in flight across the whole compute

        // S^T tile: D[key][q] = K·Q^T ; A = K-frag, B = Q-frag
        f32x4 sc[4] = {};
        __builtin_amdgcn_s_setprio(1);
#pragma unroll
        for (int kk = 0; kk < 4; ++kk) {
#pragma unroll
            for (int nt = 0; nt < 4; ++nt) {
                bf16x8 kf = *(const bf16x8*)(Ks + KSWZ(nt * 16 + l16, kk * 4 + quad));
                sc[nt] = __builtin_amdgcn_mfma_f32_16x16x32_bf16(kf, qf[kk], sc[nt], 0, 0, 0);
            }
        }
        __builtin_amdgcn_s_setprio(0);

        // online softmax (base-2; scale folded into q). keys live on regs+quads.
        // tree max (max3-fusable)
        float m0a = fmaxf(fmaxf(sc[0][0], sc[0][1]), fmaxf(sc[0][2], sc[0][3]));
        float m1a = fmaxf(fmaxf(sc[1][0], sc[1][1]), fmaxf(sc[1][2], sc[1][3]));
        float m2a = fmaxf(fmaxf(sc[2][0], sc[2][1]), fmaxf(sc[2][2], sc[2][3]));
        float m3a = fmaxf(fmaxf(sc[3][0], sc[3][1]), fmaxf(sc[3][2], sc[3][3]));
        float mx = fmaxf(fmaxf(m0a, m1a), fmaxf(m2a, m3a));
        mx = fmaxf(mx, __shfl_xor(mx, 16));
        mx = fmaxf(mx, __shfl_xor(mx, 32));
        // T13 defer-max: only rescale when the running max grew by > 8 (log2);
        // otherwise keep m_r, P values bounded by 2^8 (bf16-safe, f32 l-accum).
        if (!__all(mx - m_r <= 8.0f)) {
            float mn = fmaxf(m_r, mx);
            float alpha = exp2f(m_r - mn);
            m_r = mn;
            l_r *= alpha;
            float af4[4];
#pragma unroll
            for (int r = 0; r < 4; ++r) af4[r] = __shfl(alpha, quad * 4 + r);
#pragma unroll
            for (int dt = 0; dt < 8; ++dt)
#pragma unroll
                for (int r = 0; r < 4; ++r) o[dt][r] *= af4[r];
        }
        float rsp[4];
#pragma unroll
        for (int nt = 0; nt < 4; ++nt) {
#pragma unroll
            for (int r = 0; r < 4; ++r)
                sc[nt][r] = exp2f(sc[nt][r] - m_r);
            rsp[nt] = (sc[nt][0] + sc[nt][1]) + (sc[nt][2] + sc[nt][3]);
        }
        float rs = (rsp[0] + rsp[1]) + (rsp[2] + rsp[3]);
        rs += __shfl_xor(rs, 16);
        rs += __shfl_xor(rs, 32);
        l_r += rs;

        // P store: lane's 4 acc values = 4 consecutive keys for q-row l16 -> b64
#pragma unroll
        for (int nt = 0; nt < 4; ++nt) {
            int key0 = nt * 16 + quad * 4;
            int chunk = key0 >> 3, sub = key0 & 7;     // sub = 0 or 4
            uint2 pk;
            pk.x = pack_bf(sc[nt][0], sc[nt][1]);
            pk.y = pack_bf(sc[nt][2], sc[nt][3]);
            *(uint2*)(Pw + PSWZ(l16, chunk) + sub) = pk;
        }
        // PV: O[q][d] += P·V ; A = P-frag (m=q), B = V^T-frag (n=d)
        __builtin_amdgcn_s_setprio(1);
#pragma unroll
        for (int kk2 = 0; kk2 < 2; ++kk2) {
            bf16x8 pf = *(const bf16x8*)(Pw + PSWZ(l16, kk2 * 4 + quad));
#pragma unroll
            for (int dt = 0; dt < 8; ++dt) {
                bf16x8 vf = *(const bf16x8*)(Vs + VSWZ(dt * 16 + l16, kk2 * 4 + quad));
                o[dt] = __builtin_amdgcn_mfma_f32_16x16x32_bf16(pf, vf, o[dt], 0, 0, 0);
            }
        }
        __builtin_amdgcn_s_setprio(0);

        // all waves done reading this tile's LDS; staged regs have landed
        __syncthreads();
        if (more) {
            stage_write();               // swizzled ds_write of the prefetched tile
            __syncthreads();
        }
    }
    // epilogue: o rows are q=quad*4+r; l lives at lane l16=q -> broadcast
    float lf[4];
#pragma unroll
    for (int r = 0; r < 4; ++r) {
        float lv = __shfl(l_r, quad * 4 + r);
        lf[r] = __builtin_amdgcn_rcpf(lv);
    }
    const int b = bh >> 4, h = bh & 15;
#pragma unroll
    for (int dt = 0; dt < 8; ++dt) {
        int d = h * D_ + dt * 16 + l16;
#pragma unroll
        for (int r = 0; r < 4; ++r) {
            int s = q0 + wave * 16 + quad * 4 + r;
            yb[(size_t)(b * S_ + s) * E_ + d] = f2bf(o[dt][r] * lf[r]);
        }
    }
}

// ---------------------------------------------------------------------------
extern "C" void kernel_launch(void* const* d_in, const int* in_sizes, int n_in,
                              void* d_out, int out_size, void* d_ws, size_t ws_size,
                              hipStream_t stream)
{
    (void)in_sizes; (void)n_in; (void)out_size; (void)ws_size;
    const float* x     = (const float*)d_in[0];
    const float* cosT  = (const float*)d_in[1];
    const float* sinT  = (const float*)d_in[2];
    const float* Wqkv  = (const float*)d_in[3];
    const float* bqkv  = (const float*)d_in[4];
    const float* Wproj = (const float*)d_in[5];
    const float* bproj = (const float*)d_in[6];

    float* out  = (float*)d_out;                       // (B,S,E)
    float* kout = out  + (size_t)B_ * S_ * E_;         // (B,H,S,D)
    float* vout = kout + (size_t)B_ * S_ * E_;         // (B,H,S,D)

    u16* wqkvT  = (u16*)d_ws;                          // 6144 x 2048
    u16* wprojT = wqkvT  + (size_t)12582912;           // 2048 x 2048
    u16* qh     = wprojT + (size_t)4194304;            // (B,H,S,D)
    u16* kh     = qh     + (size_t)16777216;           // (B,H,S,D)
    u16* vt     = kh     + (size_t)16777216;           // (B,H,D,S)  V^T
    u16* yb     = vt     + (size_t)16777216;           // (B,S,E); doubles as xb
    u16* xb     = yb;                                  // x-bf16 dead before y written

    xconv_kernel<<<8192, 256, 0, stream>>>(x, xb);
    wtrans_kernel<<<dim3(96, 32), 256, 0, stream>>>(Wqkv, wqkvT, 2048, 6144);
    wtrans_kernel<<<dim3(32, 32), 256, 0, stream>>>(Wproj, wprojT, 2048, 2048);
    gemm_kernel<0><<<dim3(24, 32), 512, 0, stream>>>(
        xb, wqkvT, bqkv, qh, kh, vt, vout, nullptr, 6144, 2048);
    rotary_kernel<<<8192, 256, 0, stream>>>(qh, kh, kout, cosT, sinT);
    attn_kernel<<<dim3(32, 64), 256, 0, stream>>>(qh, kh, vt, yb);
    gemm_kernel<1><<<dim3(8, 32), 512, 0, stream>>>(
        yb, wprojT, bproj, nullptr, nullptr, nullptr, nullptr, out, 2048, 2048);
}

// Round 4
// 858.204 us; speedup vs baseline: 1.5516x; 1.5516x over previous
//
#include <hip/hip_runtime.h>

// MHA fused forward on gfx950.
// B=4, S=2048, E=2048, H=16, D=128; M = B*S = 8192.
// Outputs (concat in d_out): out (B,S,E) fp32 | k (B,H,S,D) fp32 | v (B,H,S,D) fp32.

typedef unsigned short u16;
typedef unsigned int   u32;
typedef float  f32x4  __attribute__((ext_vector_type(4)));
typedef __bf16 bf16x8 __attribute__((ext_vector_type(8)));

#define B_  4
#define S_  2048
#define E_  2048
#define H_  16
#define D_  128

__device__ __forceinline__ u16 f2bf(float f) {
    union { float f; u32 u; } v; v.f = f;
    return (u16)((v.u + 0x8000u) >> 16);
}
__device__ __forceinline__ u32 pack_bf(float a, float b) {
    union { float f; u32 u; } x, y; x.f = a; y.f = b;
    return ((x.u + 0x8000u) >> 16) | ((y.u + 0x8000u) & 0xFFFF0000u);
}
__device__ __forceinline__ float bf2f(u16 h) {
    union { u32 u; float f; } v; v.u = ((u32)h) << 16; return v.f;
}

// async global->LDS, 16B/lane. LDS dest = wave-uniform base + lane*16.
__device__ __forceinline__ void gld16(const u16* g, u16* l) {
    __builtin_amdgcn_global_load_lds(
        (const __attribute__((address_space(1))) void*)g,
        (__attribute__((address_space(3))) void*)l, 16, 0, 0);
}

// ---------------------------------------------------------------------------
// x (fp32) -> bf16, 8 elems/thread
// ---------------------------------------------------------------------------
__global__ __launch_bounds__(256) void xconv_kernel(
    const float* __restrict__ x, u16* __restrict__ xb)
{
    size_t g = (size_t)blockIdx.x * 256 + threadIdx.x;
    const float4* p = (const float4*)x + g * 2;
    float4 a = p[0], b = p[1];
    uint4 pk;
    pk.x = pack_bf(a.x, a.y); pk.y = pack_bf(a.z, a.w);
    pk.z = pack_bf(b.x, b.y); pk.w = pack_bf(b.z, b.w);
    ((uint4*)xb)[g] = pk;
}

// ---------------------------------------------------------------------------
// Transpose + convert: W (K x N fp32) -> WT (N x K bf16)
// ---------------------------------------------------------------------------
__global__ __launch_bounds__(256) void wtrans_kernel(
    const float* __restrict__ W, u16* __restrict__ WT, int K, int N)
{
    __shared__ float tile[64][65];
    const int n0 = blockIdx.x * 64, k0 = blockIdx.y * 64;
    const int t = threadIdx.x;
#pragma unroll
    for (int i = 0; i < 16; ++i) {
        int idx = i * 256 + t; int r = idx >> 6, c = idx & 63;
        tile[r][c] = W[(size_t)(k0 + r) * N + n0 + c];
    }
    __syncthreads();
#pragma unroll
    for (int i = 0; i < 16; ++i) {
        int idx = i * 256 + t; int rn = idx >> 6, ck = idx & 63;
        WT[(size_t)(n0 + rn) * K + k0 + ck] = f2bf(tile[ck][rn]);
    }
}

// ---------------------------------------------------------------------------
// GEMM: C = A (M x K bf16) * Bt^T (Bt N x K bf16).
// 256x256 tile, BK=64, 512 threads (8 waves as 2Mx4N), per-wave out 128x64.
// 8-phase (4 per K-tile) counted-vmcnt schedule (T3+T4), chunk-XOR swizzled
// LDS (T2-equivalent: chunk ^= row&7; pre-swizzled global source + linear
// global_load_lds dest), setprio(1) around MFMA clusters (T5).
// LDS = 2 dbuf x (A 32KB + B 32KB) = 128 KB -> 1 block/CU, 2 waves/SIMD.
// ---------------------------------------------------------------------------
__device__ __forceinline__ void stage_half(
    const u16* __restrict__ g, int K, u16* l, int t)
{
    const int wb = (t >> 6) << 6;          // wave*64
#pragma unroll
    for (int j = 0; j < 2; ++j) {
        const int idx = j * 512 + t;
        const int row = idx >> 3, c = (idx & 7) ^ (row & 7);
        gld16(g + (size_t)row * K + (c << 3),
              l + ((j * 512 + wb) << 3));
    }
}

template <int MODE>
__global__ __launch_bounds__(512, 2) void gemm_kernel(
    const u16* __restrict__ A, const u16* __restrict__ Bt,
    const float* __restrict__ bias,
    u16* __restrict__ qh, u16* __restrict__ kh, u16* __restrict__ vt,
    float* __restrict__ vout, float* __restrict__ outf,
    int N, int K)
{
    __shared__ u16 Asm[2][256 * 64];       // 2 x 32 KB
    __shared__ u16 Bsm[2][256 * 64];       // 2 x 32 KB

    const int t = threadIdx.x;
    const int wave = t >> 6, lane = t & 63, quad = lane >> 4, l16 = lane & 15;
    const int wr = wave >> 2, wc = wave & 3;
    const int m0 = blockIdx.y * 256, n0 = blockIdx.x * 256;
    const int NT = K >> 6;

    // swizzled read offsets: logical chunk = kk*4+quad; row&7 == l16&7
    const int sw0 = ((quad ^ (l16 & 7)) << 3);
    const int sw1 = (((4 + quad) ^ (l16 & 7)) << 3);
    const int aRow = (wr * 128 + l16) << 6;   // row*64 u16
    const int bRow = (wc * 64 + l16) << 6;

    f32x4 acc[8][4] = {};

    const u16* Ab = A  + (size_t)m0 * K;
    const u16* Bb = Bt + (size_t)n0 * K;

    // prologue: tile0 A+B, tile1 A. vmcnt(4) -> tile0 fully landed.
    stage_half(Ab,                        K, &Asm[0][0],    t);
    stage_half(Ab + (size_t)128 * K,      K, &Asm[0][8192], t);
    stage_half(Bb,                        K, &Bsm[0][0],    t);
    stage_half(Bb + (size_t)128 * K,      K, &Bsm[0][8192], t);
    stage_half(Ab + 64,                   K, &Asm[1][0],    t);
    stage_half(Ab + (size_t)128 * K + 64, K, &Asm[1][8192], t);
    asm volatile("s_waitcnt vmcnt(4)" ::: "memory");
    __builtin_amdgcn_s_barrier();

    for (int T = 0; T < NT; ++T) {
        const int cur = T & 1, nxt = cur ^ 1;
        const int kn1 = (T + 1) << 6, kn2 = (T + 2) << 6;
        const u16* Asb = &Asm[cur][0];
        const u16* Bsb = &Bsm[cur][0];
        bf16x8 af[8], b0, b1;

        // ---- phase 0: kk=0, ni=0,1 ; stage B(T+1) h0 ----
#pragma unroll
        for (int mi = 0; mi < 8; ++mi)
            af[mi] = *(const bf16x8*)(Asb + aRow + mi * 1024 + sw0);
        b0 = *(const bf16x8*)(Bsb + bRow + sw0);
        b1 = *(const bf16x8*)(Bsb + bRow + 1024 + sw0);
        if (T + 1 < NT) stage_half(Bb + kn1, K, &Bsm[nxt][0], t);
        __builtin_amdgcn_s_barrier();
        asm volatile("s_waitcnt lgkmcnt(0)" ::: "memory");
        __builtin_amdgcn_s_setprio(1);
#pragma unroll
        for (int mi = 0; mi < 8; ++mi) {
            acc[mi][0] = __builtin_amdgcn_mfma_f32_16x16x32_bf16(af[mi], b0, acc[mi][0], 0, 0, 0);
            acc[mi][1] = __builtin_amdgcn_mfma_f32_16x16x32_bf16(af[mi], b1, acc[mi][1], 0, 0, 0);
        }
        __builtin_amdgcn_s_setprio(0);
        __builtin_amdgcn_s_barrier();

        // ---- phase 1: kk=0, ni=2,3 ; stage B(T+1) h1 ----
        b0 = *(const bf16x8*)(Bsb + bRow + 2048 + sw0);
        b1 = *(const bf16x8*)(Bsb + bRow + 3072 + sw0);
        if (T + 1 < NT) stage_half(Bb + (size_t)128 * K + kn1, K, &Bsm[nxt][8192], t);
        __builtin_amdgcn_s_barrier();
        asm volatile("s_waitcnt lgkmcnt(0)" ::: "memory");
        __builtin_amdgcn_s_setprio(1);
#pragma unroll
        for (int mi = 0; mi < 8; ++mi) {
            acc[mi][2] = __builtin_amdgcn_mfma_f32_16x16x32_bf16(af[mi], b0, acc[mi][2], 0, 0, 0);
            acc[mi][3] = __builtin_amdgcn_mfma_f32_16x16x32_bf16(af[mi], b1, acc[mi][3], 0, 0, 0);
        }
        __builtin_amdgcn_s_setprio(0);
        __builtin_amdgcn_s_barrier();

        // ---- phase 2: kk=1, ni=0,1 (last ds_read of As[cur]) ----
#pragma unroll
        for (int mi = 0; mi < 8; ++mi)
            af[mi] = *(const bf16x8*)(Asb + aRow + mi * 1024 + sw1);
        b0 = *(const bf16x8*)(Bsb + bRow + sw1);
        b1 = *(const bf16x8*)(Bsb + bRow + 1024 + sw1);
        __builtin_amdgcn_s_barrier();
        asm volatile("s_waitcnt lgkmcnt(0)" ::: "memory");
        __builtin_amdgcn_s_setprio(1);
#pragma unroll
        for (int mi = 0; mi < 8; ++mi) {
            acc[mi][0] = __builtin_amdgcn_mfma_f32_16x16x32_bf16(af[mi], b0, acc[mi][0], 0, 0, 0);
            acc[mi][1] = __builtin_amdgcn_mfma_f32_16x16x32_bf16(af[mi], b1, acc[mi][1], 0, 0, 0);
        }
        __builtin_amdgcn_s_setprio(0);
        __builtin_amdgcn_s_barrier();

        // ---- phase 3: kk=1, ni=2,3 ; stage A(T+2) ; counted vmcnt ----
        b0 = *(const bf16x8*)(Bsb + bRow + 2048 + sw1);
        b1 = *(const bf16x8*)(Bsb + bRow + 3072 + sw1);
        if (T + 2 < NT) {
            stage_half(Ab + kn2,                   K, &Asm[cur][0],    t);
            stage_half(Ab + (size_t)128 * K + kn2, K, &Asm[cur][8192], t);
        }
        __builtin_amdgcn_s_barrier();
        asm volatile("s_waitcnt lgkmcnt(0)" ::: "memory");
        __builtin_amdgcn_s_setprio(1);
#pragma unroll
        for (int mi = 0; mi < 8; ++mi) {
            acc[mi][2] = __builtin_amdgcn_mfma_f32_16x16x32_bf16(af[mi], b0, acc[mi][2], 0, 0, 0);
            acc[mi][3] = __builtin_amdgcn_mfma_f32_16x16x32_bf16(af[mi], b1, acc[mi][3], 0, 0, 0);
        }
        __builtin_amdgcn_s_setprio(0);
        if (T + 2 < NT) { asm volatile("s_waitcnt vmcnt(4)" ::: "memory"); }
        else            { asm volatile("s_waitcnt vmcnt(0)" ::: "memory"); }
        __builtin_amdgcn_s_barrier();
    }

    if constexpr (MODE == 0) {
        const int sel = n0 >> 11;                  // 0=q 1=k 2=v
        const int b   = m0 >> 11, sb = m0 & 2047;
#pragma unroll
        for (int ni = 0; ni < 4; ++ni) {
            const int dg = (n0 & 2047) + wc * 64 + ni * 16 + l16;
            const int h = dg >> 7, d = dg & 127;
            const float bv = bias[n0 + wc * 64 + ni * 16 + l16];
            const size_t hb = ((size_t)(b * H_ + h)) * S_ * D_;
#pragma unroll
            for (int mi = 0; mi < 8; ++mi) {
                const int s0 = sb + wr * 128 + mi * 16 + quad * 4;
                float v0 = acc[mi][ni][0] + bv, v1 = acc[mi][ni][1] + bv;
                float v2 = acc[mi][ni][2] + bv, v3 = acc[mi][ni][3] + bv;
                size_t base = hb + (size_t)s0 * D_ + d;
                if (sel < 2) {
                    u16* dst = sel ? kh : qh;
                    dst[base]        = f2bf(v0); dst[base + D_]    = f2bf(v1);
                    dst[base + 2*D_] = f2bf(v2); dst[base + 3*D_]  = f2bf(v3);
                } else {
                    vout[base] = v0; vout[base + D_] = v1;
                    vout[base + 2*D_] = v2; vout[base + 3*D_] = v3;
                    uint2 pk; pk.x = pack_bf(v0, v1); pk.y = pack_bf(v2, v3);
                    *(uint2*)(vt + ((size_t)(b * H_ + h) * D_ + d) * S_ + s0) = pk;
                }
            }
        }
    } else {
#pragma unroll
        for (int ni = 0; ni < 4; ++ni) {
            const int col = n0 + wc * 64 + ni * 16 + l16;
            const float bv = bias[col];
#pragma unroll
            for (int mi = 0; mi < 8; ++mi) {
                const int row0 = m0 + wr * 128 + mi * 16 + quad * 4;
#pragma unroll
                for (int r = 0; r < 4; ++r)
                    outf[(size_t)(row0 + r) * N + col] = acc[mi][ni][r] + bv;
            }
        }
    }
}

// ---------------------------------------------------------------------------
// Rotary: in-place on qh/kh (bf16), k fp32 -> d_out. Folds 1/sqrt(D)*log2(e)
// into q (softmax done in base-2).
// ---------------------------------------------------------------------------
__global__ __launch_bounds__(256) void rotary_kernel(
    u16* __restrict__ q, u16* __restrict__ k, float* __restrict__ kout,
    const float* __restrict__ cosT, const float* __restrict__ sinT)
{
    const int g = blockIdx.x * 256 + threadIdx.x;
    const int d0 = (g & 15) << 3;
    const int srow = g >> 4;
    const int s = srow & (S_ - 1);
    const size_t base = (size_t)srow * D_ + d0;

    uint4 qv = *(const uint4*)(q + base);
    uint4 kv = *(const uint4*)(k + base);
    float cc[8], ss[8];
    *(float4*)(cc)     = *(const float4*)(cosT + s * D_ + d0);
    *(float4*)(cc + 4) = *(const float4*)(cosT + s * D_ + d0 + 4);
    *(float4*)(ss)     = *(const float4*)(sinT + s * D_ + d0);
    *(float4*)(ss + 4) = *(const float4*)(sinT + s * D_ + d0 + 4);
    const u16* qp = (const u16*)&qv; const u16* kp = (const u16*)&kv;
    float qo[8], ko[8];
#pragma unroll
    for (int i = 0; i < 4; ++i) {
        float q1 = bf2f(qp[2*i]), q2 = bf2f(qp[2*i+1]);
        float k1 = bf2f(kp[2*i]), k2 = bf2f(kp[2*i+1]);
        qo[2*i]   = q1 * cc[2*i]   - q2 * ss[2*i];
        qo[2*i+1] = q2 * cc[2*i+1] + q1 * ss[2*i+1];
        ko[2*i]   = k1 * cc[2*i]   - k2 * ss[2*i];
        ko[2*i+1] = k2 * cc[2*i+1] + k1 * ss[2*i+1];
    }
    const float qs_ = 0.08838834764831845f * 1.4426950408889634f; // 1/sqrt(D)*log2e
    uint4 qpk, kpk;
    u32* qq = (u32*)&qpk; u32* kq = (u32*)&kpk;
#pragma unroll
    for (int i = 0; i < 4; ++i) {
        qq[i] = pack_bf(qo[2*i] * qs_, qo[2*i+1] * qs_);
        kq[i] = pack_bf(ko[2*i], ko[2*i+1]);
    }
    *(uint4*)(q + base) = qpk;
    *(uint4*)(k + base) = kpk;
    *(float4*)(kout + base)     = make_float4(ko[0], ko[1], ko[2], ko[3]);
    *(float4*)(kout + base + 4) = make_float4(ko[4], ko[5], ko[6], ko[7]);
}

// ---------------------------------------------------------------------------
// Flash attention. Br=64 (wave = 16 q-rows), Bc=64. S^T = K*Q^T so the C
// register index runs along keys -> packed b64 P-stores + 2-shuffle softmax.
// Q frags direct from global. Single-buffered swizzled LDS (40 KB -> 4
// blocks/CU for TLP) + T14 async-STAGE split with EIGHT NAMED uint4 locals
// (no arrays/lambdas -> no scratch; R3's lambda-captured arrays spilled,
// WRITE_SIZE 1.85 GB): tile t+1 issued to regs before computing tile t;
// after the barrier the regs are ds_written (swizzle on the write address).
// T13 defer-max (THR=8, base-2). T5 setprio around MFMA clusters.
// ---------------------------------------------------------------------------
#define KSWZ(row, c) ((row) * 128 + (((c) ^ ((row) & 7)) << 3))  // 64 x 16-chunk
#define VSWZ(d, c)   ((d) * 64 + (((c) ^ ((d) & 7)) << 3))       // 128 x 8-chunk
#define PSWZ(qr, c)  ((qr) * 64 + (((c) ^ ((qr) & 7)) << 3))     // 16 x 8-chunk

// issue-early: 8 x global_load_dwordx4 into named regs
#define STAGE_LOAD(k0_) do {                                                  \
    const u16* kp_ = kb + (size_t)((k0_) + krow) * D_ + (kc << 3);            \
    sk0 = *(const uint4*)(kp_);                                               \
    sk1 = *(const uint4*)(kp_ + 16 * D_);                                     \
    sk2 = *(const uint4*)(kp_ + 32 * D_);                                     \
    sk3 = *(const uint4*)(kp_ + 48 * D_);                                     \
    const u16* vp_ = vb + (size_t)vrow * S_ + (k0_) + (vc << 3);              \
    sv0 = *(const uint4*)(vp_);                                               \
    sv1 = *(const uint4*)(vp_ + (size_t)32 * S_);                             \
    sv2 = *(const uint4*)(vp_ + (size_t)64 * S_);                             \
    sv3 = *(const uint4*)(vp_ + (size_t)96 * S_);                             \
} while (0)

// write-late: swizzled ds_write_b128 of the staged regs
#define STAGE_WRITE() do {                                                    \
    *(uint4*)(Ks + KSWZ(krow,      kc)) = sk0;                                \
    *(uint4*)(Ks + KSWZ(krow + 16, kc)) = sk1;                                \
    *(uint4*)(Ks + KSWZ(krow + 32, kc)) = sk2;                                \
    *(uint4*)(Ks + KSWZ(krow + 48, kc)) = sk3;                                \
    *(uint4*)(Vs + VSWZ(vrow,      vc)) = sv0;                                \
    *(uint4*)(Vs + VSWZ(vrow + 32, vc)) = sv1;                                \
    *(uint4*)(Vs + VSWZ(vrow + 64, vc)) = sv2;                                \
    *(uint4*)(Vs + VSWZ(vrow + 96, vc)) = sv3;                                \
} while (0)

__global__ __launch_bounds__(256, 4) void attn_kernel(
    const u16* __restrict__ qh, const u16* __restrict__ kh,
    const u16* __restrict__ vt, u16* __restrict__ yb)
{
    __shared__ u16 Ks[64 * 128];        // 16 KB
    __shared__ u16 Vs[128 * 64];        // 16 KB  (V^T tile [d][key])
    __shared__ u16 Ps[4 * 16 * 64];     //  8 KB  (per-wave P [q][key])

    const int t = threadIdx.x, wave = t >> 6, lane = t & 63;
    const int quad = lane >> 4, l16 = lane & 15;
    const int bh = blockIdx.y, q0 = blockIdx.x * 64;
    const u16* kb = kh + (size_t)bh * S_ * D_;
    const u16* vb = vt + (size_t)bh * D_ * S_;
    u16* Pw = Ps + wave * (16 * 64);

    // per-thread staging addresses (linear global; swizzle applied on ds_write)
    const int krow = t >> 4, kc = t & 15;          // K: 16 rows x 16 chunks
    const int vrow = t >> 3, vc = t & 7;           // V^T: 32 d-rows x 8 chunks
    uint4 sk0, sk1, sk2, sk3, sv0, sv1, sv2, sv3;  // named -> stay in VGPRs

    // Q fragments (B-operand layout: n=l16 q-row, k=quad*8) straight from global
    bf16x8 qf[4];
    {
        const u16* qp = qh + ((size_t)bh * S_ + q0 + wave * 16 + l16) * D_ + quad * 8;
#pragma unroll
        for (int kk = 0; kk < 4; ++kk) qf[kk] = *(const bf16x8*)(qp + kk * 32);
    }

    f32x4 o[8] = {};
    float m_r = -1e30f, l_r = 0.f;      // per-lane: q-row = l16 (replicated over quads)

    STAGE_LOAD(0);
    STAGE_WRITE();                       // compiler inserts vmcnt before use
    __syncthreads();

    for (int k0 = 0; k0 < S_; k0 += 64) {
        const bool more = (k0 + 64 < S_);
        if (more) STAGE_LOAD(k0 + 64);   // in flight across the whole compute

        // S^T tile: D[key][q] = K·Q^T ; A = K-frag, B = Q-frag
        f32x4 sc[4] = {};
        __builtin_amdgcn_s_setprio(1);
#pragma unroll
        for (int kk = 0; kk < 4; ++kk) {
#pragma unroll
            for (int nt = 0; nt < 4; ++nt) {
                bf16x8 kf = *(const bf16x8*)(Ks + KSWZ(nt * 16 + l16, kk * 4 + quad));
                sc[nt] = __builtin_amdgcn_mfma_f32_16x16x32_bf16(kf, qf[kk], sc[nt], 0, 0, 0);
            }
        }
        __builtin_amdgcn_s_setprio(0);

        // online softmax (base-2; scale folded into q). keys live on regs+quads.
        float m0a = fmaxf(fmaxf(sc[0][0], sc[0][1]), fmaxf(sc[0][2], sc[0][3]));
        float m1a = fmaxf(fmaxf(sc[1][0], sc[1][1]), fmaxf(sc[1][2], sc[1][3]));
        float m2a = fmaxf(fmaxf(sc[2][0], sc[2][1]), fmaxf(sc[2][2], sc[2][3]));
        float m3a = fmaxf(fmaxf(sc[3][0], sc[3][1]), fmaxf(sc[3][2], sc[3][3]));
        float mx = fmaxf(fmaxf(m0a, m1a), fmaxf(m2a, m3a));
        mx = fmaxf(mx, __shfl_xor(mx, 16));
        mx = fmaxf(mx, __shfl_xor(mx, 32));
        // T13 defer-max: only rescale when the running max grew by > 8 (log2);
        // otherwise keep m_r, P values bounded by 2^8 (bf16-safe, f32 l-accum).
        if (!__all(mx - m_r <= 8.0f)) {
            float mn = fmaxf(m_r, mx);
            float alpha = exp2f(m_r - mn);
            m_r = mn;
            l_r *= alpha;
            float af4[4];
#pragma unroll
            for (int r = 0; r < 4; ++r) af4[r] = __shfl(alpha, quad * 4 + r);
#pragma unroll
            for (int dt = 0; dt < 8; ++dt)
#pragma unroll
                for (int r = 0; r < 4; ++r) o[dt][r] *= af4[r];
        }
        float rsp[4];
#pragma unroll
        for (int nt = 0; nt < 4; ++nt) {
#pragma unroll
            for (int r = 0; r < 4; ++r)
                sc[nt][r] = exp2f(sc[nt][r] - m_r);
            rsp[nt] = (sc[nt][0] + sc[nt][1]) + (sc[nt][2] + sc[nt][3]);
        }
        float rs = (rsp[0] + rsp[1]) + (rsp[2] + rsp[3]);
        rs += __shfl_xor(rs, 16);
        rs += __shfl_xor(rs, 32);
        l_r += rs;

        // P store: lane's 4 acc values = 4 consecutive keys for q-row l16 -> b64
#pragma unroll
        for (int nt = 0; nt < 4; ++nt) {
            int key0 = nt * 16 + quad * 4;
            int chunk = key0 >> 3, sub = key0 & 7;     // sub = 0 or 4
            uint2 pk;
            pk.x = pack_bf(sc[nt][0], sc[nt][1]);
            pk.y = pack_bf(sc[nt][2], sc[nt][3]);
            *(uint2*)(Pw + PSWZ(l16, chunk) + sub) = pk;
        }
        // PV: O[q][d] += P·V ; A = P-frag (m=q), B = V^T-frag (n=d)
        __builtin_amdgcn_s_setprio(1);
#pragma unroll
        for (int kk2 = 0; kk2 < 2; ++kk2) {
            bf16x8 pf = *(const bf16x8*)(Pw + PSWZ(l16, kk2 * 4 + quad));
#pragma unroll
            for (int dt = 0; dt < 8; ++dt) {
                bf16x8 vf = *(const bf16x8*)(Vs + VSWZ(dt * 16 + l16, kk2 * 4 + quad));
                o[dt] = __builtin_amdgcn_mfma_f32_16x16x32_bf16(pf, vf, o[dt], 0, 0, 0);
            }
        }
        __builtin_amdgcn_s_setprio(0);

        // all waves done reading this tile's LDS; staged regs have landed
        __syncthreads();
        if (more) {
            STAGE_WRITE();               // swizzled ds_write of the prefetched tile
            __syncthreads();
        }
    }
    // epilogue: o rows are q=quad*4+r; l lives at lane l16=q -> broadcast
    float lf[4];
#pragma unroll
    for (int r = 0; r < 4; ++r) {
        float lv = __shfl(l_r, quad * 4 + r);
        lf[r] = __builtin_amdgcn_rcpf(lv);
    }
    const int b = bh >> 4, h = bh & 15;
#pragma unroll
    for (int dt = 0; dt < 8; ++dt) {
        int d = h * D_ + dt * 16 + l16;
#pragma unroll
        for (int r = 0; r < 4; ++r) {
            int s = q0 + wave * 16 + quad * 4 + r;
            yb[(size_t)(b * S_ + s) * E_ + d] = f2bf(o[dt][r] * lf[r]);
        }
    }
}

// ---------------------------------------------------------------------------
extern "C" void kernel_launch(void* const* d_in, const int* in_sizes, int n_in,
                              void* d_out, int out_size, void* d_ws, size_t ws_size,
                              hipStream_t stream)
{
    (void)in_sizes; (void)n_in; (void)out_size; (void)ws_size;
    const float* x     = (const float*)d_in[0];
    const float* cosT  = (const float*)d_in[1];
    const float* sinT  = (const float*)d_in[2];
    const float* Wqkv  = (const float*)d_in[3];
    const float* bqkv  = (const float*)d_in[4];
    const float* Wproj = (const float*)d_in[5];
    const float* bproj = (const float*)d_in[6];

    float* out  = (float*)d_out;                       // (B,S,E)
    float* kout = out  + (size_t)B_ * S_ * E_;         // (B,H,S,D)
    float* vout = kout + (size_t)B_ * S_ * E_;         // (B,H,S,D)

    u16* wqkvT  = (u16*)d_ws;                          // 6144 x 2048
    u16* wprojT = wqkvT  + (size_t)12582912;           // 2048 x 2048
    u16* qh     = wprojT + (size_t)4194304;            // (B,H,S,D)
    u16* kh     = qh     + (size_t)16777216;           // (B,H,S,D)
    u16* vt     = kh     + (size_t)16777216;           // (B,H,D,S)  V^T
    u16* yb     = vt     + (size_t)16777216;           // (B,S,E); doubles as xb
    u16* xb     = yb;                                  // x-bf16 dead before y written

    xconv_kernel<<<8192, 256, 0, stream>>>(x, xb);
    wtrans_kernel<<<dim3(96, 32), 256, 0, stream>>>(Wqkv, wqkvT, 2048, 6144);
    wtrans_kernel<<<dim3(32, 32), 256, 0, stream>>>(Wproj, wprojT, 2048, 2048);
    gemm_kernel<0><<<dim3(24, 32), 512, 0, stream>>>(
        xb, wqkvT, bqkv, qh, kh, vt, vout, nullptr, 6144, 2048);
    rotary_kernel<<<8192, 256, 0, stream>>>(qh, kh, kout, cosT, sinT);
    attn_kernel<<<dim3(32, 64), 256, 0, stream>>>(qh, kh, vt, yb);
    gemm_kernel<1><<<dim3(8, 32), 512, 0, stream>>>(
        yb, wprojT, bproj, nullptr, nullptr, nullptr, nullptr, out, 2048, 2048);
}

// Round 5
// 828.881 us; speedup vs baseline: 1.6065x; 1.0354x over previous
//
#include <hip/hip_runtime.h>

// MHA fused forward on gfx950.
// B=4, S=2048, E=2048, H=16, D=128; M = B*S = 8192.
// Outputs (concat in d_out): out (B,S,E) fp32 | k (B,H,S,D) fp32 | v (B,H,S,D) fp32.

typedef unsigned short u16;
typedef unsigned int   u32;
typedef float  f32x4  __attribute__((ext_vector_type(4)));
typedef __bf16 bf16x8 __attribute__((ext_vector_type(8)));

#define B_  4
#define S_  2048
#define E_  2048
#define H_  16
#define D_  128

__device__ __forceinline__ u16 f2bf(float f) {
    union { float f; u32 u; } v; v.f = f;
    return (u16)((v.u + 0x8000u) >> 16);
}
__device__ __forceinline__ u32 pack_bf(float a, float b) {
    union { float f; u32 u; } x, y; x.f = a; y.f = b;
    return ((x.u + 0x8000u) >> 16) | ((y.u + 0x8000u) & 0xFFFF0000u);
}
__device__ __forceinline__ float bf2f(u16 h) {
    union { u32 u; float f; } v; v.u = ((u32)h) << 16; return v.f;
}
// single-instruction f32 pair -> packed bf16 (RTNE); low16 <- a, high16 <- b
__device__ __forceinline__ u32 cvtpk_bf16(float a, float b) {
    u32 r;
    asm("v_cvt_pk_bf16_f32 %0, %1, %2" : "=v"(r) : "v"(a), "v"(b));
    return r;
}

// async global->LDS, 16B/lane. LDS dest = wave-uniform base + lane*16.
__device__ __forceinline__ void gld16(const u16* g, u16* l) {
    __builtin_amdgcn_global_load_lds(
        (const __attribute__((address_space(1))) void*)g,
        (__attribute__((address_space(3))) void*)l, 16, 0, 0);
}

// ---------------------------------------------------------------------------
// x (fp32) -> bf16, 8 elems/thread
// ---------------------------------------------------------------------------
__global__ __launch_bounds__(256) void xconv_kernel(
    const float* __restrict__ x, u16* __restrict__ xb)
{
    size_t g = (size_t)blockIdx.x * 256 + threadIdx.x;
    const float4* p = (const float4*)x + g * 2;
    float4 a = p[0], b = p[1];
    uint4 pk;
    pk.x = pack_bf(a.x, a.y); pk.y = pack_bf(a.z, a.w);
    pk.z = pack_bf(b.x, b.y); pk.w = pack_bf(b.z, b.w);
    ((uint4*)xb)[g] = pk;
}

// ---------------------------------------------------------------------------
// Transpose + convert: W (K x N fp32) -> WT (N x K bf16)
// ---------------------------------------------------------------------------
__global__ __launch_bounds__(256) void wtrans_kernel(
    const float* __restrict__ W, u16* __restrict__ WT, int K, int N)
{
    __shared__ float tile[64][65];
    const int n0 = blockIdx.x * 64, k0 = blockIdx.y * 64;
    const int t = threadIdx.x;
#pragma unroll
    for (int i = 0; i < 16; ++i) {
        int idx = i * 256 + t; int r = idx >> 6, c = idx & 63;
        tile[r][c] = W[(size_t)(k0 + r) * N + n0 + c];
    }
    __syncthreads();
#pragma unroll
    for (int i = 0; i < 16; ++i) {
        int idx = i * 256 + t; int rn = idx >> 6, ck = idx & 63;
        WT[(size_t)(n0 + rn) * K + k0 + ck] = f2bf(tile[ck][rn]);
    }
}

// ---------------------------------------------------------------------------
// GEMM: C = A (M x K bf16) * Bt^T (Bt N x K bf16).
// 256x256 tile, BK=64, 512 threads (8 waves as 2Mx4N), per-wave out 128x64.
// 8-phase (4 per K-tile) counted-vmcnt schedule (T3+T4), chunk-XOR swizzled
// LDS (T2-equivalent: chunk ^= row&7; pre-swizzled global source + linear
// global_load_lds dest), setprio(1) around MFMA clusters (T5).
// LDS = 2 dbuf x (A 32KB + B 32KB) = 128 KB -> 1 block/CU, 2 waves/SIMD.
// ---------------------------------------------------------------------------
__device__ __forceinline__ void stage_half(
    const u16* __restrict__ g, int K, u16* l, int t)
{
    const int wb = (t >> 6) << 6;          // wave*64
#pragma unroll
    for (int j = 0; j < 2; ++j) {
        const int idx = j * 512 + t;
        const int row = idx >> 3, c = (idx & 7) ^ (row & 7);
        gld16(g + (size_t)row * K + (c << 3),
              l + ((j * 512 + wb) << 3));
    }
}

template <int MODE>
__global__ __launch_bounds__(512, 2) void gemm_kernel(
    const u16* __restrict__ A, const u16* __restrict__ Bt,
    const float* __restrict__ bias,
    u16* __restrict__ qh, u16* __restrict__ kh, u16* __restrict__ vt,
    float* __restrict__ vout, float* __restrict__ outf,
    int N, int K)
{
    __shared__ u16 Asm[2][256 * 64];       // 2 x 32 KB
    __shared__ u16 Bsm[2][256 * 64];       // 2 x 32 KB

    const int t = threadIdx.x;
    const int wave = t >> 6, lane = t & 63, quad = lane >> 4, l16 = lane & 15;
    const int wr = wave >> 2, wc = wave & 3;
    const int m0 = blockIdx.y * 256, n0 = blockIdx.x * 256;
    const int NT = K >> 6;

    // swizzled read offsets: logical chunk = kk*4+quad; row&7 == l16&7
    const int sw0 = ((quad ^ (l16 & 7)) << 3);
    const int sw1 = (((4 + quad) ^ (l16 & 7)) << 3);
    const int aRow = (wr * 128 + l16) << 6;   // row*64 u16
    const int bRow = (wc * 64 + l16) << 6;

    f32x4 acc[8][4] = {};

    const u16* Ab = A  + (size_t)m0 * K;
    const u16* Bb = Bt + (size_t)n0 * K;

    // prologue: tile0 A+B, tile1 A. vmcnt(4) -> tile0 fully landed.
    stage_half(Ab,                        K, &Asm[0][0],    t);
    stage_half(Ab + (size_t)128 * K,      K, &Asm[0][8192], t);
    stage_half(Bb,                        K, &Bsm[0][0],    t);
    stage_half(Bb + (size_t)128 * K,      K, &Bsm[0][8192], t);
    stage_half(Ab + 64,                   K, &Asm[1][0],    t);
    stage_half(Ab + (size_t)128 * K + 64, K, &Asm[1][8192], t);
    asm volatile("s_waitcnt vmcnt(4)" ::: "memory");
    __builtin_amdgcn_s_barrier();

    for (int T = 0; T < NT; ++T) {
        const int cur = T & 1, nxt = cur ^ 1;
        const int kn1 = (T + 1) << 6, kn2 = (T + 2) << 6;
        const u16* Asb = &Asm[cur][0];
        const u16* Bsb = &Bsm[cur][0];
        bf16x8 af[8], b0, b1;

        // ---- phase 0: kk=0, ni=0,1 ; stage B(T+1) h0 ----
#pragma unroll
        for (int mi = 0; mi < 8; ++mi)
            af[mi] = *(const bf16x8*)(Asb + aRow + mi * 1024 + sw0);
        b0 = *(const bf16x8*)(Bsb + bRow + sw0);
        b1 = *(const bf16x8*)(Bsb + bRow + 1024 + sw0);
        if (T + 1 < NT) stage_half(Bb + kn1, K, &Bsm[nxt][0], t);
        __builtin_amdgcn_s_barrier();
        asm volatile("s_waitcnt lgkmcnt(0)" ::: "memory");
        __builtin_amdgcn_s_setprio(1);
#pragma unroll
        for (int mi = 0; mi < 8; ++mi) {
            acc[mi][0] = __builtin_amdgcn_mfma_f32_16x16x32_bf16(af[mi], b0, acc[mi][0], 0, 0, 0);
            acc[mi][1] = __builtin_amdgcn_mfma_f32_16x16x32_bf16(af[mi], b1, acc[mi][1], 0, 0, 0);
        }
        __builtin_amdgcn_s_setprio(0);
        __builtin_amdgcn_s_barrier();

        // ---- phase 1: kk=0, ni=2,3 ; stage B(T+1) h1 ----
        b0 = *(const bf16x8*)(Bsb + bRow + 2048 + sw0);
        b1 = *(const bf16x8*)(Bsb + bRow + 3072 + sw0);
        if (T + 1 < NT) stage_half(Bb + (size_t)128 * K + kn1, K, &Bsm[nxt][8192], t);
        __builtin_amdgcn_s_barrier();
        asm volatile("s_waitcnt lgkmcnt(0)" ::: "memory");
        __builtin_amdgcn_s_setprio(1);
#pragma unroll
        for (int mi = 0; mi < 8; ++mi) {
            acc[mi][2] = __builtin_amdgcn_mfma_f32_16x16x32_bf16(af[mi], b0, acc[mi][2], 0, 0, 0);
            acc[mi][3] = __builtin_amdgcn_mfma_f32_16x16x32_bf16(af[mi], b1, acc[mi][3], 0, 0, 0);
        }
        __builtin_amdgcn_s_setprio(0);
        __builtin_amdgcn_s_barrier();

        // ---- phase 2: kk=1, ni=0,1 (last ds_read of As[cur]) ----
#pragma unroll
        for (int mi = 0; mi < 8; ++mi)
            af[mi] = *(const bf16x8*)(Asb + aRow + mi * 1024 + sw1);
        b0 = *(const bf16x8*)(Bsb + bRow + sw1);
        b1 = *(const bf16x8*)(Bsb + bRow + 1024 + sw1);
        __builtin_amdgcn_s_barrier();
        asm volatile("s_waitcnt lgkmcnt(0)" ::: "memory");
        __builtin_amdgcn_s_setprio(1);
#pragma unroll
        for (int mi = 0; mi < 8; ++mi) {
            acc[mi][0] = __builtin_amdgcn_mfma_f32_16x16x32_bf16(af[mi], b0, acc[mi][0], 0, 0, 0);
            acc[mi][1] = __builtin_amdgcn_mfma_f32_16x16x32_bf16(af[mi], b1, acc[mi][1], 0, 0, 0);
        }
        __builtin_amdgcn_s_setprio(0);
        __builtin_amdgcn_s_barrier();

        // ---- phase 3: kk=1, ni=2,3 ; stage A(T+2) ; counted vmcnt ----
        b0 = *(const bf16x8*)(Bsb + bRow + 2048 + sw1);
        b1 = *(const bf16x8*)(Bsb + bRow + 3072 + sw1);
        if (T + 2 < NT) {
            stage_half(Ab + kn2,                   K, &Asm[cur][0],    t);
            stage_half(Ab + (size_t)128 * K + kn2, K, &Asm[cur][8192], t);
        }
        __builtin_amdgcn_s_barrier();
        asm volatile("s_waitcnt lgkmcnt(0)" ::: "memory");
        __builtin_amdgcn_s_setprio(1);
#pragma unroll
        for (int mi = 0; mi < 8; ++mi) {
            acc[mi][2] = __builtin_amdgcn_mfma_f32_16x16x32_bf16(af[mi], b0, acc[mi][2], 0, 0, 0);
            acc[mi][3] = __builtin_amdgcn_mfma_f32_16x16x32_bf16(af[mi], b1, acc[mi][3], 0, 0, 0);
        }
        __builtin_amdgcn_s_setprio(0);
        if (T + 2 < NT) { asm volatile("s_waitcnt vmcnt(4)" ::: "memory"); }
        else            { asm volatile("s_waitcnt vmcnt(0)" ::: "memory"); }
        __builtin_amdgcn_s_barrier();
    }

    if constexpr (MODE == 0) {
        const int sel = n0 >> 11;                  // 0=q 1=k 2=v
        const int b   = m0 >> 11, sb = m0 & 2047;
#pragma unroll
        for (int ni = 0; ni < 4; ++ni) {
            const int dg = (n0 & 2047) + wc * 64 + ni * 16 + l16;
            const int h = dg >> 7, d = dg & 127;
            const float bv = bias[n0 + wc * 64 + ni * 16 + l16];
            const size_t hb = ((size_t)(b * H_ + h)) * S_ * D_;
#pragma unroll
            for (int mi = 0; mi < 8; ++mi) {
                const int s0 = sb + wr * 128 + mi * 16 + quad * 4;
                float v0 = acc[mi][ni][0] + bv, v1 = acc[mi][ni][1] + bv;
                float v2 = acc[mi][ni][2] + bv, v3 = acc[mi][ni][3] + bv;
                size_t base = hb + (size_t)s0 * D_ + d;
                if (sel < 2) {
                    u16* dst = sel ? kh : qh;
                    dst[base]        = f2bf(v0); dst[base + D_]    = f2bf(v1);
                    dst[base + 2*D_] = f2bf(v2); dst[base + 3*D_]  = f2bf(v3);
                } else {
                    vout[base] = v0; vout[base + D_] = v1;
                    vout[base + 2*D_] = v2; vout[base + 3*D_] = v3;
                    uint2 pk; pk.x = pack_bf(v0, v1); pk.y = pack_bf(v2, v3);
                    *(uint2*)(vt + ((size_t)(b * H_ + h) * D_ + d) * S_ + s0) = pk;
                }
            }
        }
    } else {
#pragma unroll
        for (int ni = 0; ni < 4; ++ni) {
            const int col = n0 + wc * 64 + ni * 16 + l16;
            const float bv = bias[col];
#pragma unroll
            for (int mi = 0; mi < 8; ++mi) {
                const int row0 = m0 + wr * 128 + mi * 16 + quad * 4;
#pragma unroll
                for (int r = 0; r < 4; ++r)
                    outf[(size_t)(row0 + r) * N + col] = acc[mi][ni][r] + bv;
            }
        }
    }
}

// ---------------------------------------------------------------------------
// Rotary: in-place on qh/kh (bf16), k fp32 -> d_out. Folds 1/sqrt(D)*log2(e)
// into q (softmax done in base-2).
// ---------------------------------------------------------------------------
__global__ __launch_bounds__(256) void rotary_kernel(
    u16* __restrict__ q, u16* __restrict__ k, float* __restrict__ kout,
    const float* __restrict__ cosT, const float* __restrict__ sinT)
{
    const int g = blockIdx.x * 256 + threadIdx.x;
    const int d0 = (g & 15) << 3;
    const int srow = g >> 4;
    const int s = srow & (S_ - 1);
    const size_t base = (size_t)srow * D_ + d0;

    uint4 qv = *(const uint4*)(q + base);
    uint4 kv = *(const uint4*)(k + base);
    float cc[8], ss[8];
    *(float4*)(cc)     = *(const float4*)(cosT + s * D_ + d0);
    *(float4*)(cc + 4) = *(const float4*)(cosT + s * D_ + d0 + 4);
    *(float4*)(ss)     = *(const float4*)(sinT + s * D_ + d0);
    *(float4*)(ss + 4) = *(const float4*)(sinT + s * D_ + d0 + 4);
    const u16* qp = (const u16*)&qv; const u16* kp = (const u16*)&kv;
    float qo[8], ko[8];
#pragma unroll
    for (int i = 0; i < 4; ++i) {
        float q1 = bf2f(qp[2*i]), q2 = bf2f(qp[2*i+1]);
        float k1 = bf2f(kp[2*i]), k2 = bf2f(kp[2*i+1]);
        qo[2*i]   = q1 * cc[2*i]   - q2 * ss[2*i];
        qo[2*i+1] = q2 * cc[2*i+1] + q1 * ss[2*i+1];
        ko[2*i]   = k1 * cc[2*i]   - k2 * ss[2*i];
        ko[2*i+1] = k2 * cc[2*i+1] + k1 * ss[2*i+1];
    }
    const float qs_ = 0.08838834764831845f * 1.4426950408889634f; // 1/sqrt(D)*log2e
    uint4 qpk, kpk;
    u32* qq = (u32*)&qpk; u32* kq = (u32*)&kpk;
#pragma unroll
    for (int i = 0; i < 4; ++i) {
        qq[i] = pack_bf(qo[2*i] * qs_, qo[2*i+1] * qs_);
        kq[i] = pack_bf(ko[2*i], ko[2*i+1]);
    }
    *(uint4*)(q + base) = qpk;
    *(uint4*)(k + base) = kpk;
    *(float4*)(kout + base)     = make_float4(ko[0], ko[1], ko[2], ko[3]);
    *(float4*)(kout + base + 4) = make_float4(ko[4], ko[5], ko[6], ko[7]);
}

// ---------------------------------------------------------------------------
// Flash attention. Br=64 (wave = 16 q-rows), Bc=64. S^T = K*Q^T so the C
// register index runs along keys -> packed b64 P-stores + 2-shuffle softmax.
// Q frags direct from global; K and V^T staged via global_load_lds into
// XOR-swizzled LDS (single buffer, 40 KB -> 4 blocks/CU: TLP hides staging —
// verified R1 vs R4 equivalence). XCD-bijective grid swizzle: each XCD owns
// 8 heads and walks one head's 32 q-blocks consecutively -> K/V L2-resident
// per XCD (attacks the 3x K/V over-fetch seen in FETCH_SIZE).
// T13 defer-max (THR=8, base-2). T5 setprio. P pack via v_cvt_pk_bf16_f32.
// ---------------------------------------------------------------------------
#define KSWZ(row, c) ((row) * 128 + (((c) ^ ((row) & 7)) << 3))  // 64 x 16-chunk
#define VSWZ(d, c)   ((d) * 64 + (((c) ^ ((d) & 7)) << 3))       // 128 x 8-chunk
#define PSWZ(qr, c)  ((qr) * 64 + (((c) ^ ((qr) & 7)) << 3))     // 16 x 8-chunk

__global__ __launch_bounds__(256, 4) void attn_kernel(
    const u16* __restrict__ qh, const u16* __restrict__ kh,
    const u16* __restrict__ vt, u16* __restrict__ yb)
{
    __shared__ u16 Ks[64 * 128];        // 16 KB
    __shared__ u16 Vs[128 * 64];        // 16 KB  (V^T tile [d][key])
    __shared__ u16 Ps[4 * 16 * 64];     //  8 KB  (per-wave P [q][key])

    const int t = threadIdx.x, wave = t >> 6, lane = t & 63;
    const int quad = lane >> 4, l16 = lane & 15;
    // XCD-bijective swizzle (2048 blocks, 8 XCDs, xcd = bid%8 round-robin):
    // XCD c gets heads c*8..c*8+7; within an XCD, one head's 32 q-blocks are
    // consecutive in dispatch order -> 512 KB K/V working set per XCD.
    const int bid = blockIdx.x;
    const int jj = bid >> 3;
    const int bh = (bid & 7) * 8 + (jj >> 5);
    const int q0 = (jj & 31) << 6;
    const u16* kb = kh + (size_t)bh * S_ * D_;
    const u16* vb = vt + (size_t)bh * D_ * S_;
    u16* Pw = Ps + wave * (16 * 64);

    // Q fragments (B-operand layout: n=l16 q-row, k=quad*8) straight from global
    bf16x8 qf[4];
    {
        const u16* qp = qh + ((size_t)bh * S_ + q0 + wave * 16 + l16) * D_ + quad * 8;
#pragma unroll
        for (int kk = 0; kk < 4; ++kk) qf[kk] = *(const bf16x8*)(qp + kk * 32);
    }

    f32x4 o[8] = {};
    float m_r = -1e30f, l_r = 0.f;      // per-lane: q-row = l16 (replicated over quads)

    for (int k0 = 0; k0 < S_; k0 += 64) {
        __syncthreads();                // prior iter's LDS reads done
#pragma unroll
        for (int i = 0; i < 4; ++i) {
            int idx = i * 256 + t;
            {   // K rows [k0,k0+64) x 128d, swizzle folded into source chunk
                int row = idx >> 4, c = (idx & 15) ^ (row & 7);
                gld16(kb + (size_t)(k0 + row) * D_ + (c << 3),
                      Ks + ((i * 256 + wave * 64) << 3));
            }
            {   // V^T [128d][64 keys]
                int d = idx >> 3, c = (idx & 7) ^ (d & 7);
                gld16(vb + (size_t)d * S_ + k0 + (c << 3),
                      Vs + ((i * 256 + wave * 64) << 3));
            }
        }
        __syncthreads();

        // S^T tile: D[key][q] = K·Q^T ; A = K-frag, B = Q-frag
        f32x4 sc[4] = {};
        __builtin_amdgcn_s_setprio(1);
#pragma unroll
        for (int kk = 0; kk < 4; ++kk) {
#pragma unroll
            for (int nt = 0; nt < 4; ++nt) {
                bf16x8 kf = *(const bf16x8*)(Ks + KSWZ(nt * 16 + l16, kk * 4 + quad));
                sc[nt] = __builtin_amdgcn_mfma_f32_16x16x32_bf16(kf, qf[kk], sc[nt], 0, 0, 0);
            }
        }
        __builtin_amdgcn_s_setprio(0);

        // online softmax (base-2; scale folded into q). keys live on regs+quads.
        // max tree written as fused pairs -> v_max3
        float mx = fmaxf(sc[0][0], sc[0][1]);
        mx = fmaxf(fmaxf(mx, sc[0][2]), sc[0][3]);
        mx = fmaxf(fmaxf(mx, sc[1][0]), sc[1][1]);
        mx = fmaxf(fmaxf(mx, sc[1][2]), sc[1][3]);
        mx = fmaxf(fmaxf(mx, sc[2][0]), sc[2][1]);
        mx = fmaxf(fmaxf(mx, sc[2][2]), sc[2][3]);
        mx = fmaxf(fmaxf(mx, sc[3][0]), sc[3][1]);
        mx = fmaxf(fmaxf(mx, sc[3][2]), sc[3][3]);
        mx = fmaxf(mx, __shfl_xor(mx, 16));
        mx = fmaxf(mx, __shfl_xor(mx, 32));
        // T13 defer-max: only rescale when the running max grew by > 8 (log2);
        // otherwise keep m_r, P values bounded by 2^8 (bf16-safe, f32 l-accum).
        if (!__all(mx - m_r <= 8.0f)) {
            float mn = fmaxf(m_r, mx);
            float alpha = exp2f(m_r - mn);
            m_r = mn;
            l_r *= alpha;
            float af4[4];
#pragma unroll
            for (int r = 0; r < 4; ++r) af4[r] = __shfl(alpha, quad * 4 + r);
#pragma unroll
            for (int dt = 0; dt < 8; ++dt)
#pragma unroll
                for (int r = 0; r < 4; ++r) o[dt][r] *= af4[r];
        }
        float rsp[4];
#pragma unroll
        for (int nt = 0; nt < 4; ++nt) {
#pragma unroll
            for (int r = 0; r < 4; ++r)
                sc[nt][r] = exp2f(sc[nt][r] - m_r);
            rsp[nt] = (sc[nt][0] + sc[nt][1]) + (sc[nt][2] + sc[nt][3]);
        }
        float rs = (rsp[0] + rsp[1]) + (rsp[2] + rsp[3]);
        rs += __shfl_xor(rs, 16);
        rs += __shfl_xor(rs, 32);
        l_r += rs;

        // P store: lane's 4 acc values = 4 consecutive keys for q-row l16 -> b64
#pragma unroll
        for (int nt = 0; nt < 4; ++nt) {
            int key0 = nt * 16 + quad * 4;
            int chunk = key0 >> 3, sub = key0 & 7;     // sub = 0 or 4
            uint2 pk;
            pk.x = cvtpk_bf16(sc[nt][0], sc[nt][1]);
            pk.y = cvtpk_bf16(sc[nt][2], sc[nt][3]);
            *(uint2*)(Pw + PSWZ(l16, chunk) + sub) = pk;
        }
        // PV: O[q][d] += P·V ; A = P-frag (m=q), B = V^T-frag (n=d)
        __builtin_amdgcn_s_setprio(1);
#pragma unroll
        for (int kk2 = 0; kk2 < 2; ++kk2) {
            bf16x8 pf = *(const bf16x8*)(Pw + PSWZ(l16, kk2 * 4 + quad));
#pragma unroll
            for (int dt = 0; dt < 8; ++dt) {
                bf16x8 vf = *(const bf16x8*)(Vs + VSWZ(dt * 16 + l16, kk2 * 4 + quad));
                o[dt] = __builtin_amdgcn_mfma_f32_16x16x32_bf16(pf, vf, o[dt], 0, 0, 0);
            }
        }
        __builtin_amdgcn_s_setprio(0);
    }
    // epilogue: o rows are q=quad*4+r; l lives at lane l16=q -> broadcast
    float lf[4];
#pragma unroll
    for (int r = 0; r < 4; ++r) {
        float lv = __shfl(l_r, quad * 4 + r);
        lf[r] = __builtin_amdgcn_rcpf(lv);
    }
    const int b = bh >> 4, h = bh & 15;
#pragma unroll
    for (int dt = 0; dt < 8; ++dt) {
        int d = h * D_ + dt * 16 + l16;
#pragma unroll
        for (int r = 0; r < 4; ++r) {
            int s = q0 + wave * 16 + quad * 4 + r;
            yb[(size_t)(b * S_ + s) * E_ + d] = f2bf(o[dt][r] * lf[r]);
        }
    }
}

// ---------------------------------------------------------------------------
extern "C" void kernel_launch(void* const* d_in, const int* in_sizes, int n_in,
                              void* d_out, int out_size, void* d_ws, size_t ws_size,
                              hipStream_t stream)
{
    (void)in_sizes; (void)n_in; (void)out_size; (void)ws_size;
    const float* x     = (const float*)d_in[0];
    const float* cosT  = (const float*)d_in[1];
    const float* sinT  = (const float*)d_in[2];
    const float* Wqkv  = (const float*)d_in[3];
    const float* bqkv  = (const float*)d_in[4];
    const float* Wproj = (const float*)d_in[5];
    const float* bproj = (const float*)d_in[6];

    float* out  = (float*)d_out;                       // (B,S,E)
    float* kout = out  + (size_t)B_ * S_ * E_;         // (B,H,S,D)
    float* vout = kout + (size_t)B_ * S_ * E_;         // (B,H,S,D)

    u16* wqkvT  = (u16*)d_ws;                          // 6144 x 2048
    u16* wprojT = wqkvT  + (size_t)12582912;           // 2048 x 2048
    u16* qh     = wprojT + (size_t)4194304;            // (B,H,S,D)
    u16* kh     = qh     + (size_t)16777216;           // (B,H,S,D)
    u16* vt     = kh     + (size_t)16777216;           // (B,H,D,S)  V^T
    u16* yb     = vt     + (size_t)16777216;           // (B,S,E); doubles as xb
    u16* xb     = yb;                                  // x-bf16 dead before y written

    xconv_kernel<<<8192, 256, 0, stream>>>(x, xb);
    wtrans_kernel<<<dim3(96, 32), 256, 0, stream>>>(Wqkv, wqkvT, 2048, 6144);
    wtrans_kernel<<<dim3(32, 32), 256, 0, stream>>>(Wproj, wprojT, 2048, 2048);
    gemm_kernel<0><<<dim3(24, 32), 512, 0, stream>>>(
        xb, wqkvT, bqkv, qh, kh, vt, vout, nullptr, 6144, 2048);
    rotary_kernel<<<8192, 256, 0, stream>>>(qh, kh, kout, cosT, sinT);
    attn_kernel<<<2048, 256, 0, stream>>>(qh, kh, vt, yb);
    gemm_kernel<1><<<dim3(8, 32), 512, 0, stream>>>(
        yb, wprojT, bproj, nullptr, nullptr, nullptr, nullptr, out, 2048, 2048);
}